// Round 1
// baseline (199.969 us; speedup 1.0000x reference)
//
#include <hip/hip_runtime.h>
#include <hip/hip_bf16.h>

// Problem: x (16,1024,512) fp32.
//   sq = rowsum(x^2); gram = X X^T (batched); d = max(0, sq_i+sq_j-2*gram)
//   global mean/var over all 16M d values; d_hat=(d-mean)*rsqrt(var+eps)
//   out = softmax(-(d_hat*gamma+beta)/TEMP, axis=-1)
// Softmax is shift-invariant => mean and beta cancel. Only
// scale = gamma*rsqrt(var+eps)/TEMP matters. var needs global sum(d), sum(d^2)
// (fp64: E[d^2]~1.05e6 vs var~4096 -> cancellation needs f64 accumulation).

#define S_DIM 1024
#define E_DIM 512
#define NBATCH 16
#define BM 128
#define BK 32
#define TEMP_C 13.544f

typedef __attribute__((ext_vector_type(4))) float f32x4;
typedef __attribute__((ext_vector_type(8))) short bf16x8;

__device__ inline unsigned pkbf(float lo, float hi) {
  unsigned a = __float_as_uint(lo), b = __float_as_uint(hi);
  a = (a + 0x7FFFu + ((a >> 16) & 1u)) >> 16;          // RNE bf16 of lo
  b = (b + 0x7FFFu + ((b >> 16) & 1u)) & 0xFFFF0000u;  // RNE bf16 of hi << 16
  return b | a;
}

// Kernel 1: sq[row] = sum_k x[row][k]^2 for 16384 rows; also zero the f64 sums.
__global__ __launch_bounds__(256) void sq_kernel(const float* __restrict__ x,
                                                 float* __restrict__ sq,
                                                 double* __restrict__ sums) {
  int row = blockIdx.x * 4 + (threadIdx.x >> 6);
  int lane = threadIdx.x & 63;
  const float4* xr = reinterpret_cast<const float4*>(x + (size_t)row * E_DIM);
  float4 a = xr[lane];
  float4 b = xr[lane + 64];
  float s = a.x * a.x + a.y * a.y + a.z * a.z + a.w * a.w +
            b.x * b.x + b.y * b.y + b.z * b.z + b.w * b.w;
#pragma unroll
  for (int o = 32; o > 0; o >>= 1) s += __shfl_xor(s, o);
  if (lane == 0) sq[row] = s;
  if (blockIdx.x == 0 && threadIdx.x == 0) { sums[0] = 0.0; sums[1] = 0.0; }
}

// Kernel 2: batched gram via bf16 MFMA, 128x128 tile, BK=32, 4 waves (2x2),
// each wave 64x64 via 4x4 frags of 16x16x32. Register-staged fp32->bf16
// conversion into double-buffered LDS. Epilogue: d=max(0,sq_i+sq_j-2g),
// write fp32 to d_out, accumulate sum(d),sum(d^2) in f64 -> atomicAdd.
__global__ __launch_bounds__(256, 2) void gram_kernel(const float* __restrict__ x,
                                                      const float* __restrict__ sq,
                                                      float* __restrict__ dout,
                                                      double* __restrict__ sums) {
  __shared__ short ldsA[2][BM][BK];
  __shared__ short ldsB[2][BM][BK];
  __shared__ double red[8];

  const int b = blockIdx.x >> 6;
  const int tile = blockIdx.x & 63;
  const int tr = tile >> 3, tc = tile & 7;
  const int tid = threadIdx.x;
  const int wave = tid >> 6, lane = tid & 63;
  const int wr = wave >> 1, wc = wave & 1;

  const float* xb = x + (size_t)b * S_DIM * E_DIM;
  const int rowA0 = tr * BM, rowB0 = tc * BM;

  f32x4 acc[4][4] = {};

  auto stage = [&](int buf, int k0) {
#pragma unroll
    for (int i = 0; i < 4; ++i) {
      int c = tid + 256 * i;          // 1024 chunks of 4 floats per tile
      int row = c >> 3;
      int c4 = (c & 7) * 4;
      float4 va = *reinterpret_cast<const float4*>(xb + (size_t)(rowA0 + row) * E_DIM + k0 + c4);
      float4 vb = *reinterpret_cast<const float4*>(xb + (size_t)(rowB0 + row) * E_DIM + k0 + c4);
      *reinterpret_cast<uint2*>(&ldsA[buf][row][c4]) =
          make_uint2(pkbf(va.x, va.y), pkbf(va.z, va.w));
      *reinterpret_cast<uint2*>(&ldsB[buf][row][c4]) =
          make_uint2(pkbf(vb.x, vb.y), pkbf(vb.z, vb.w));
    }
  };

  stage(0, 0);
  __syncthreads();
  int buf = 0;
#pragma unroll 1
  for (int ks = 0; ks < E_DIM / BK; ++ks) {
    bf16x8 af[4], bfr[4];
#pragma unroll
    for (int m = 0; m < 4; ++m)
      af[m] = *reinterpret_cast<const bf16x8*>(
          &ldsA[buf][wr * 64 + m * 16 + (lane & 15)][(lane >> 4) * 8]);
#pragma unroll
    for (int n = 0; n < 4; ++n)
      bfr[n] = *reinterpret_cast<const bf16x8*>(
          &ldsB[buf][wc * 64 + n * 16 + (lane & 15)][(lane >> 4) * 8]);

    if (ks + 1 < E_DIM / BK) stage(buf ^ 1, (ks + 1) * BK);

#pragma unroll
    for (int m = 0; m < 4; ++m)
#pragma unroll
      for (int n = 0; n < 4; ++n)
        acc[m][n] = __builtin_amdgcn_mfma_f32_16x16x32_bf16(af[m], bfr[n], acc[m][n], 0, 0, 0);
    __syncthreads();
    buf ^= 1;
  }

  // Epilogue. C/D frag layout (m89): col = lane&15, row = (lane>>4)*4 + reg.
  const float* sqb = sq + b * S_DIM;
  float* dbase = dout + (size_t)b * S_DIM * S_DIM;
  double sd = 0.0, sd2 = 0.0;
#pragma unroll
  for (int m = 0; m < 4; ++m) {
    int gr0 = tr * BM + wr * 64 + m * 16 + ((lane >> 4) << 2);
    float sqr0 = sqb[gr0 + 0], sqr1 = sqb[gr0 + 1], sqr2 = sqb[gr0 + 2], sqr3 = sqb[gr0 + 3];
#pragma unroll
    for (int n = 0; n < 4; ++n) {
      int gc = tc * BM + wc * 64 + n * 16 + (lane & 15);
      float sqc = sqb[gc];
      float d0 = fmaxf(sqr0 + sqc - 2.0f * acc[m][n][0], 0.0f);
      float d1 = fmaxf(sqr1 + sqc - 2.0f * acc[m][n][1], 0.0f);
      float d2 = fmaxf(sqr2 + sqc - 2.0f * acc[m][n][2], 0.0f);
      float d3 = fmaxf(sqr3 + sqc - 2.0f * acc[m][n][3], 0.0f);
      dbase[(size_t)(gr0 + 0) * S_DIM + gc] = d0;
      dbase[(size_t)(gr0 + 1) * S_DIM + gc] = d1;
      dbase[(size_t)(gr0 + 2) * S_DIM + gc] = d2;
      dbase[(size_t)(gr0 + 3) * S_DIM + gc] = d3;
      sd += (double)d0 + (double)d1 + (double)d2 + (double)d3;
      sd2 += (double)d0 * d0 + (double)d1 * d1 + (double)d2 * d2 + (double)d3 * d3;
    }
  }
#pragma unroll
  for (int o = 32; o > 0; o >>= 1) {
    sd += __shfl_xor(sd, o);
    sd2 += __shfl_xor(sd2, o);
  }
  if (lane == 0) { red[wave] = sd; red[4 + wave] = sd2; }
  __syncthreads();
  if (tid == 0) {
    atomicAdd(&sums[0], red[0] + red[1] + red[2] + red[3]);
    atomicAdd(&sums[1], red[4] + red[5] + red[6] + red[7]);
  }
}

// Kernel 3: in-place row softmax of logits = -scale*d (mean/beta cancel).
__global__ __launch_bounds__(256) void softmax_kernel(float* __restrict__ d,
                                                      const double* __restrict__ sums,
                                                      const float* __restrict__ gamma) {
  constexpr double invN = 1.0 / (16.0 * 1024.0 * 1024.0);
  double mean = sums[0] * invN;
  double var = sums[1] * invN - mean * mean;
  float scale = (float)(-((double)gamma[0]) / (sqrt(var + 1e-5) * (double)TEMP_C));

  float* row = d + (size_t)blockIdx.x * S_DIM;
  int tid = threadIdx.x, lane = tid & 63, wave = tid >> 6;
  float4 v = reinterpret_cast<float4*>(row)[tid];
  float l0 = scale * v.x, l1 = scale * v.y, l2 = scale * v.z, l3 = scale * v.w;
  float mx = fmaxf(fmaxf(l0, l1), fmaxf(l2, l3));
#pragma unroll
  for (int o = 32; o > 0; o >>= 1) mx = fmaxf(mx, __shfl_xor(mx, o));
  __shared__ float s1[4], s2[4];
  if (lane == 0) s1[wave] = mx;
  __syncthreads();
  mx = fmaxf(fmaxf(s1[0], s1[1]), fmaxf(s1[2], s1[3]));
  const float L2E = 1.4426950408889634f;
  float e0 = exp2f((l0 - mx) * L2E);
  float e1 = exp2f((l1 - mx) * L2E);
  float e2 = exp2f((l2 - mx) * L2E);
  float e3 = exp2f((l3 - mx) * L2E);
  float s = e0 + e1 + e2 + e3;
#pragma unroll
  for (int o = 32; o > 0; o >>= 1) s += __shfl_xor(s, o);
  if (lane == 0) s2[wave] = s;
  __syncthreads();
  s = s2[0] + s2[1] + s2[2] + s2[3];
  float inv = 1.0f / s;
  reinterpret_cast<float4*>(row)[tid] = make_float4(e0 * inv, e1 * inv, e2 * inv, e3 * inv);
}

extern "C" void kernel_launch(void* const* d_in, const int* in_sizes, int n_in,
                              void* d_out, int out_size, void* d_ws, size_t ws_size,
                              hipStream_t stream) {
  const float* x = (const float*)d_in[0];
  const float* gamma = (const float*)d_in[1];
  // beta (d_in[2]) cancels in softmax; unused.
  float* out = (float*)d_out;
  double* sums = (double*)d_ws;                       // 2 doubles
  float* sq = (float*)((char*)d_ws + 256);            // 16384 floats

  sq_kernel<<<dim3(NBATCH * S_DIM / 4), dim3(256), 0, stream>>>(x, sq, sums);
  gram_kernel<<<dim3(NBATCH * 64), dim3(256), 0, stream>>>(x, sq, out, sums);
  softmax_kernel<<<dim3(NBATCH * S_DIM), dim3(256), 0, stream>>>(out, sums, gamma);
}

// Round 2
// 157.195 us; speedup vs baseline: 1.2721x; 1.2721x over previous
//
#include <hip/hip_runtime.h>
#include <hip/hip_bf16.h>

// x (16,1024,512) fp32 -> d = max(0, sq_i+sq_j-2*X X^T) per batch
// global mean/var LayerNorm -> softmax(-(d_hat*gamma+beta)/TEMP, axis=-1).
// Softmax is shift-invariant => mean & beta cancel; only
// scale = gamma*rsqrt(var+eps)/TEMP survives. var needs global sum(d),sum(d^2)
// in f64 (E[d^2]~1.05e6 vs var~4e3 -> cancellation).
//
// Pipeline: (1) sqcvt: x->bf16 (ws) + row sq + zero sums   [~48 MB traffic]
//           (2) gram2: m97-structure MFMA GEMM, global_load_lds w16,
//               swizzled LDS (pre-swizzled global source), XCD-aware block
//               map (2 batches/XCD -> slab L2-resident), fused d-epilogue
//               + f64 reduction
//           (3) softmax2: one row per wave, no barriers/LDS.

#define S_DIM 1024
#define E_DIM 512
#define NBATCH 16
#define TEMP_C 13.544

typedef __attribute__((ext_vector_type(4))) float f32x4;
typedef __attribute__((ext_vector_type(8))) short bf16x8;

__device__ inline unsigned pkbf(float lo, float hi) {
  unsigned a = __float_as_uint(lo), b = __float_as_uint(hi);
  a = (a + 0x7FFFu + ((a >> 16) & 1u)) >> 16;          // RNE bf16 of lo
  b = (b + 0x7FFFu + ((b >> 16) & 1u)) & 0xFFFF0000u;  // RNE bf16 of hi << 16
  return b | a;
}

__device__ inline void gload16(const void* g, void* l) {
  __builtin_amdgcn_global_load_lds(
      (const __attribute__((address_space(1))) unsigned*)g,
      (__attribute__((address_space(3))) unsigned*)l, 16, 0, 0);
}

// ---------------- Kernel 1: fp32->bf16 convert + row square-sums ------------
__global__ __launch_bounds__(256) void sqcvt(const float* __restrict__ x,
                                             ushort* __restrict__ xb16,
                                             float* __restrict__ sq,
                                             double* __restrict__ sums) {
  const int wave = threadIdx.x >> 6, lane = threadIdx.x & 63;
  const size_t row = (size_t)blockIdx.x * 4 + wave;
  const float4* xr = reinterpret_cast<const float4*>(x + row * E_DIM);
  float4 a = xr[lane * 2], b = xr[lane * 2 + 1];
  uint4 p;
  p.x = pkbf(a.x, a.y); p.y = pkbf(a.z, a.w);
  p.z = pkbf(b.x, b.y); p.w = pkbf(b.z, b.w);
  *reinterpret_cast<uint4*>(xb16 + row * E_DIM + lane * 8) = p;
  float s = a.x*a.x + a.y*a.y + a.z*a.z + a.w*a.w +
            b.x*b.x + b.y*b.y + b.z*b.z + b.w*b.w;
#pragma unroll
  for (int o = 32; o > 0; o >>= 1) s += __shfl_xor(s, o);
  if (lane == 0) sq[row] = s;
  if (blockIdx.x == 0 && threadIdx.x == 0) { sums[0] = 0.0; sums[1] = 0.0; }
}

// ---------------- Kernel 2: gram via bf16 MFMA (m97 structure) --------------
// 128x128 tile, BK=32, 4 waves (2x2), global_load_lds w16 into linear LDS,
// XOR-swizzle ((row>>1)&3 on 16B col-slot) applied to BOTH global source and
// ds_read (rule 21) -> 2-way conflicts (free). Epilogue d=max(0,sqi+sqj-2g).
__global__ __launch_bounds__(256) void gram2(const ushort* __restrict__ xb16,
                                             const float* __restrict__ sq,
                                             float* __restrict__ dout,
                                             double* __restrict__ sums) {
  __shared__ ushort lA[128 * 32];
  __shared__ ushort lB[128 * 32];
  __shared__ double red[8];

  const int tid = threadIdx.x, wave = tid >> 6, lane = tid & 63;
  const int wr = wave >> 1, wc = wave & 1;

  // XCD-aware map: xcd = bid&7 (dispatch round-robin), 2 batches per XCD so
  // each batch's 1 MB bf16 slab stays L2-resident on its XCD.
  const int bid = blockIdx.x;
  const int xcd = bid & 7, li = bid >> 3;
  const int b = (xcd << 1) | (li >> 6);
  const int tile = li & 63;
  const int tr = tile >> 3, tc = tile & 7;

  const ushort* xb = xb16 + (size_t)b * (S_DIM * E_DIM);
  const int rowA0 = tr * 128, rowB0 = tc * 128;

  // Per-thread pre-swizzled global source offsets. LDS slot o (bytes) holds
  // logical offset so = o ^ (((o>>7)&3)<<4)  (involution: bits4-5 ^= row>>1).
  int eA[2], eB[2];
  const int o0 = wave * 1024 + lane * 16;
#pragma unroll
  for (int i = 0; i < 2; ++i) {
    int o = o0 + i * 4096;
    int so = o ^ (((o >> 7) & 3) << 4);
    int row = so >> 6, cb = (so >> 4) & 3;
    eA[i] = (rowA0 + row) * E_DIM + cb * 8;
    eB[i] = (rowB0 + row) * E_DIM + cb * 8;
  }

  f32x4 acc[4][4] = {};

#pragma unroll 1
  for (int ks = 0; ks < E_DIM / 32; ++ks) {
    const int k0 = ks * 32;
    gload16(xb + eA[0] + k0, (char*)lA + wave * 1024);
    gload16(xb + eA[1] + k0, (char*)lA + 4096 + wave * 1024);
    gload16(xb + eB[0] + k0, (char*)lB + wave * 1024);
    gload16(xb + eB[1] + k0, (char*)lB + 4096 + wave * 1024);
    __syncthreads();
    bf16x8 af[4], bfr[4];
    const int cb = lane >> 4;
#pragma unroll
    for (int m = 0; m < 4; ++m) {
      int row = wr * 64 + m * 16 + (lane & 15);
      af[m] = *reinterpret_cast<const bf16x8*>(
          (const char*)lA + row * 64 + ((cb ^ ((row >> 1) & 3)) << 4));
    }
#pragma unroll
    for (int n = 0; n < 4; ++n) {
      int row = wc * 64 + n * 16 + (lane & 15);
      bfr[n] = *reinterpret_cast<const bf16x8*>(
          (const char*)lB + row * 64 + ((cb ^ ((row >> 1) & 3)) << 4));
    }
#pragma unroll
    for (int m = 0; m < 4; ++m)
#pragma unroll
      for (int n = 0; n < 4; ++n)
        acc[m][n] = __builtin_amdgcn_mfma_f32_16x16x32_bf16(af[m], bfr[n], acc[m][n], 0, 0, 0);
    __syncthreads();
  }

  // Epilogue (C/D layout col=lane&15, row=(lane>>4)*4+reg; gram symmetric).
  const float* sqb = sq + b * S_DIM;
  float* dbase = dout + (size_t)b * S_DIM * S_DIM;
  double sd = 0.0, sd2 = 0.0;
#pragma unroll
  for (int m = 0; m < 4; ++m) {
    int gr0 = tr * 128 + wr * 64 + m * 16 + ((lane >> 4) << 2);
    float sqr0 = sqb[gr0], sqr1 = sqb[gr0 + 1], sqr2 = sqb[gr0 + 2], sqr3 = sqb[gr0 + 3];
#pragma unroll
    for (int n = 0; n < 4; ++n) {
      int gc = tc * 128 + wc * 64 + n * 16 + (lane & 15);
      float sqc = sqb[gc];
      float d0 = fmaxf(sqr0 + sqc - 2.0f * acc[m][n][0], 0.0f);
      float d1 = fmaxf(sqr1 + sqc - 2.0f * acc[m][n][1], 0.0f);
      float d2 = fmaxf(sqr2 + sqc - 2.0f * acc[m][n][2], 0.0f);
      float d3 = fmaxf(sqr3 + sqc - 2.0f * acc[m][n][3], 0.0f);
      dbase[(size_t)(gr0 + 0) * S_DIM + gc] = d0;
      dbase[(size_t)(gr0 + 1) * S_DIM + gc] = d1;
      dbase[(size_t)(gr0 + 2) * S_DIM + gc] = d2;
      dbase[(size_t)(gr0 + 3) * S_DIM + gc] = d3;
      sd += (double)d0 + (double)d1 + (double)d2 + (double)d3;
      sd2 += (double)d0 * d0 + (double)d1 * d1 + (double)d2 * d2 + (double)d3 * d3;
    }
  }
#pragma unroll
  for (int o = 32; o > 0; o >>= 1) {
    sd += __shfl_xor(sd, o);
    sd2 += __shfl_xor(sd2, o);
  }
  if (lane == 0) { red[wave] = sd; red[4 + wave] = sd2; }
  __syncthreads();
  if (tid == 0) {
    atomicAdd(&sums[0], red[0] + red[1] + red[2] + red[3]);
    atomicAdd(&sums[1], red[4] + red[5] + red[6] + red[7]);
  }
}

// ------------- Fallback gram (register-staged bf16 cvt), small ws -----------
__global__ __launch_bounds__(256) void sq_kernel(const float* __restrict__ x,
                                                 float* __restrict__ sq,
                                                 double* __restrict__ sums) {
  int row = blockIdx.x * 4 + (threadIdx.x >> 6);
  int lane = threadIdx.x & 63;
  const float4* xr = reinterpret_cast<const float4*>(x + (size_t)row * E_DIM);
  float4 a = xr[lane], b = xr[lane + 64];
  float s = a.x*a.x + a.y*a.y + a.z*a.z + a.w*a.w +
            b.x*b.x + b.y*b.y + b.z*b.z + b.w*b.w;
#pragma unroll
  for (int o = 32; o > 0; o >>= 1) s += __shfl_xor(s, o);
  if (lane == 0) sq[row] = s;
  if (blockIdx.x == 0 && threadIdx.x == 0) { sums[0] = 0.0; sums[1] = 0.0; }
}

__global__ __launch_bounds__(256, 2) void gram_fb(const float* __restrict__ x,
                                                  const float* __restrict__ sq,
                                                  float* __restrict__ dout,
                                                  double* __restrict__ sums) {
  __shared__ short ldsA[2][128][32];
  __shared__ short ldsB[2][128][32];
  __shared__ double red[8];
  const int b = blockIdx.x >> 6;
  const int tile = blockIdx.x & 63;
  const int tr = tile >> 3, tc = tile & 7;
  const int tid = threadIdx.x;
  const int wave = tid >> 6, lane = tid & 63;
  const int wr = wave >> 1, wc = wave & 1;
  const float* xb = x + (size_t)b * S_DIM * E_DIM;
  const int rowA0 = tr * 128, rowB0 = tc * 128;
  f32x4 acc[4][4] = {};
  auto stage = [&](int buf, int k0) {
#pragma unroll
    for (int i = 0; i < 4; ++i) {
      int c = tid + 256 * i;
      int row = c >> 3;
      int c4 = (c & 7) * 4;
      float4 va = *reinterpret_cast<const float4*>(xb + (size_t)(rowA0 + row) * E_DIM + k0 + c4);
      float4 vb = *reinterpret_cast<const float4*>(xb + (size_t)(rowB0 + row) * E_DIM + k0 + c4);
      *reinterpret_cast<uint2*>(&ldsA[buf][row][c4]) = make_uint2(pkbf(va.x, va.y), pkbf(va.z, va.w));
      *reinterpret_cast<uint2*>(&ldsB[buf][row][c4]) = make_uint2(pkbf(vb.x, vb.y), pkbf(vb.z, vb.w));
    }
  };
  stage(0, 0);
  __syncthreads();
  int buf = 0;
#pragma unroll 1
  for (int ks = 0; ks < E_DIM / 32; ++ks) {
    bf16x8 af[4], bfr[4];
#pragma unroll
    for (int m = 0; m < 4; ++m)
      af[m] = *reinterpret_cast<const bf16x8*>(&ldsA[buf][wr*64 + m*16 + (lane&15)][(lane>>4)*8]);
#pragma unroll
    for (int n = 0; n < 4; ++n)
      bfr[n] = *reinterpret_cast<const bf16x8*>(&ldsB[buf][wc*64 + n*16 + (lane&15)][(lane>>4)*8]);
    if (ks + 1 < E_DIM / 32) stage(buf ^ 1, (ks + 1) * 32);
#pragma unroll
    for (int m = 0; m < 4; ++m)
#pragma unroll
      for (int n = 0; n < 4; ++n)
        acc[m][n] = __builtin_amdgcn_mfma_f32_16x16x32_bf16(af[m], bfr[n], acc[m][n], 0, 0, 0);
    __syncthreads();
    buf ^= 1;
  }
  const float* sqb = sq + b * S_DIM;
  float* dbase = dout + (size_t)b * S_DIM * S_DIM;
  double sd = 0.0, sd2 = 0.0;
#pragma unroll
  for (int m = 0; m < 4; ++m) {
    int gr0 = tr * 128 + wr * 64 + m * 16 + ((lane >> 4) << 2);
    float sqr0 = sqb[gr0], sqr1 = sqb[gr0+1], sqr2 = sqb[gr0+2], sqr3 = sqb[gr0+3];
#pragma unroll
    for (int n = 0; n < 4; ++n) {
      int gc = tc * 128 + wc * 64 + n * 16 + (lane & 15);
      float sqc = sqb[gc];
      float d0 = fmaxf(sqr0 + sqc - 2.0f * acc[m][n][0], 0.0f);
      float d1 = fmaxf(sqr1 + sqc - 2.0f * acc[m][n][1], 0.0f);
      float d2 = fmaxf(sqr2 + sqc - 2.0f * acc[m][n][2], 0.0f);
      float d3 = fmaxf(sqr3 + sqc - 2.0f * acc[m][n][3], 0.0f);
      dbase[(size_t)(gr0+0)*S_DIM + gc] = d0;
      dbase[(size_t)(gr0+1)*S_DIM + gc] = d1;
      dbase[(size_t)(gr0+2)*S_DIM + gc] = d2;
      dbase[(size_t)(gr0+3)*S_DIM + gc] = d3;
      sd += (double)d0 + (double)d1 + (double)d2 + (double)d3;
      sd2 += (double)d0*d0 + (double)d1*d1 + (double)d2*d2 + (double)d3*d3;
    }
  }
#pragma unroll
  for (int o = 32; o > 0; o >>= 1) { sd += __shfl_xor(sd, o); sd2 += __shfl_xor(sd2, o); }
  if (lane == 0) { red[wave] = sd; red[4 + wave] = sd2; }
  __syncthreads();
  if (tid == 0) {
    atomicAdd(&sums[0], red[0] + red[1] + red[2] + red[3]);
    atomicAdd(&sums[1], red[4] + red[5] + red[6] + red[7]);
  }
}

// ---------------- Kernel 3: row softmax, one row per wave -------------------
__global__ __launch_bounds__(256) void softmax2(float* __restrict__ d,
                                                const double* __restrict__ sums,
                                                const float* __restrict__ gamma) {
  const int wave = threadIdx.x >> 6, lane = threadIdx.x & 63;
  const size_t row = (size_t)blockIdx.x * 4 + wave;
  constexpr double invN = 1.0 / (16.0 * 1024.0 * 1024.0);
  double mean = sums[0] * invN;
  double var = sums[1] * invN - mean * mean;
  float scale = (float)(-((double)gamma[0]) / (sqrt(var + 1e-5) * TEMP_C));

  float4* r4 = reinterpret_cast<float4*>(d + row * S_DIM);
  float4 v[4];
#pragma unroll
  for (int i = 0; i < 4; ++i) v[i] = r4[lane + 64 * i];
  float l[16];
#pragma unroll
  for (int i = 0; i < 4; ++i) {
    l[4*i+0] = scale * v[i].x; l[4*i+1] = scale * v[i].y;
    l[4*i+2] = scale * v[i].z; l[4*i+3] = scale * v[i].w;
  }
  float mx = l[0];
#pragma unroll
  for (int i = 1; i < 16; ++i) mx = fmaxf(mx, l[i]);
#pragma unroll
  for (int o = 32; o > 0; o >>= 1) mx = fmaxf(mx, __shfl_xor(mx, o));
  const float L2E = 1.4426950408889634f;
  float e[16], s = 0.f;
#pragma unroll
  for (int i = 0; i < 16; ++i) { e[i] = exp2f((l[i] - mx) * L2E); s += e[i]; }
#pragma unroll
  for (int o = 32; o > 0; o >>= 1) s += __shfl_xor(s, o);
  float inv = 1.0f / s;
#pragma unroll
  for (int i = 0; i < 4; ++i)
    r4[lane + 64 * i] = make_float4(e[4*i]*inv, e[4*i+1]*inv, e[4*i+2]*inv, e[4*i+3]*inv);
}

extern "C" void kernel_launch(void* const* d_in, const int* in_sizes, int n_in,
                              void* d_out, int out_size, void* d_ws, size_t ws_size,
                              hipStream_t stream) {
  const float* x = (const float*)d_in[0];
  const float* gamma = (const float*)d_in[1];
  float* out = (float*)d_out;
  double* sums = (double*)d_ws;                              // 2 doubles @0
  float* sq = (float*)((char*)d_ws + 256);                   // 16384 floats
  ushort* xb16 = (ushort*)((char*)d_ws + 256 + 65536);       // 16 MB bf16 x
  const size_t need = 256 + 65536 + (size_t)NBATCH * S_DIM * E_DIM * 2;

  if (ws_size >= need) {
    sqcvt<<<dim3(NBATCH * S_DIM / 4), dim3(256), 0, stream>>>(x, xb16, sq, sums);
    gram2<<<dim3(NBATCH * 64), dim3(256), 0, stream>>>(xb16, sq, out, sums);
  } else {
    sq_kernel<<<dim3(NBATCH * S_DIM / 4), dim3(256), 0, stream>>>(x, sq, sums);
    gram_fb<<<dim3(NBATCH * 64), dim3(256), 0, stream>>>(x, sq, out, sums);
  }
  softmax2<<<dim3(NBATCH * S_DIM / 4), dim3(256), 0, stream>>>(out, sums, gamma);
}